// Round 2
// baseline (162.646 us; speedup 1.0000x reference)
//
#include <hip/hip_runtime.h>
#include <hip/hip_bf16.h>
#include <stdint.h>

// scores[b,q,k] = dot(Q[b,q,:],K[b,k,:]) / (max(|Qrow|,eps)*max(|Krow|,eps)); mask==0 -> -1e9
// B=4, Sq=Sk=2048, D=1024, fp32 in/out.
//
// R8: counted-vmcnt pipeline (T3+T4). R7 post-mortem: launch_bounds(256,4) changed
//     nothing (occ 32, MfmaUtil 24, 54.6us) -> m97-structure ceiling (full vmcnt(0)
//     drain per K-step) is the limiter, not residency. New GEMM:
//     256x256 tile, 512 thr (8 waves 2Mx4N), BK=32, TRIPLE-buffered LDS (96KB).
//     While computing tile t from buf[t%3], stage tile t+2 into buf[(t+2)%3];
//     boundary wait = s_waitcnt vmcnt(4) (tile t+1 landed, t+2 in flight).
//     One raw s_barrier per K-tile, no vmcnt(0) in main loop (T4).
//     Swizzle for 64B rows: pos p of row r holds chunk p ^ ((r>>1)&3) ->
//     wave64 ds_read_b128 spreads 8 lanes per 4-bank group = 2-way = free.
//     MFMA 32x32x16, frag/epilogue mapping identical to verified R6.
// Pass 1: fp32 -> bf16 in d_ws + row inv-norms (unchanged).
// Fallback (ws too small): R1 single-kernel bf16, LDK=40 (unchanged).

constexpr int B_  = 4;
constexpr int SQ  = 2048;
constexpr int SK  = 2048;
constexpr int D_  = 1024;

// fallback geometry
constexpr int BM  = 128;
constexpr int BN  = 128;

// R8 main-path geometry
constexpr int BM2 = 256;
constexpr int BN2 = 256;
constexpr int BK2 = 32;                  // K-tile: 64 B rows = 4 x 16B chunks
constexpr int NT2 = D_ / BK2;            // 32 K-tiles
constexpr int BUFSH     = BM2 * BK2;     // 8192 shorts per A (or B) tile
constexpr int BUFSTRIDE = 2 * BUFSH;     // 16384 shorts per buffer (A then B)

typedef __attribute__((ext_vector_type(8)))  short    short8;
typedef __attribute__((ext_vector_type(4)))  float    f32x4;
typedef __attribute__((ext_vector_type(16))) float    f32x16;
typedef __attribute__((ext_vector_type(4)))  unsigned uint4v;
typedef unsigned int u32;

__device__ inline unsigned pack_bf16(float lo, float hi) {
  union { float f; unsigned u; } a, b;
  a.f = lo; b.f = hi;
  return __builtin_amdgcn_perm(b.u, a.u, 0x07060302u);
}

__device__ inline void async_ld16(const void* g, void* l) {
  __builtin_amdgcn_global_load_lds((const __attribute__((address_space(1))) u32*)g,
                                   (__attribute__((address_space(3))) u32*)l, 16, 0, 0);
}

// ---------------- Pass 1: convert + norms ----------------
constexpr int ROWS_Q = B_ * SQ;           // 8192
constexpr int ROWS_T = B_ * (SQ + SK);    // 16384

__global__ __launch_bounds__(256) void convert_norm(
    const float* __restrict__ Q, const float* __restrict__ Km,
    unsigned short* __restrict__ Qb, unsigned short* __restrict__ Kb,
    float* __restrict__ invQ, float* __restrict__ invK)
{
  const int row  = blockIdx.x * 4 + (threadIdx.x >> 6);
  const int lane = threadIdx.x & 63;

  const float* src; unsigned short* dst; float* inv;
  if (row < ROWS_Q) {
    src = Q  + (size_t)row * D_;
    dst = Qb + (size_t)row * D_;
    inv = invQ + row;
  } else {
    int r = row - ROWS_Q;
    src = Km + (size_t)r * D_;
    dst = Kb + (size_t)r * D_;
    inv = invK + r;
  }

  const f32x4* s4 = (const f32x4*)(src + lane * 16);
  f32x4 v[4];
  #pragma unroll
  for (int i = 0; i < 4; ++i) v[i] = s4[i];

  float ss = 0.0f;
  unsigned p[8];
  #pragma unroll
  for (int i = 0; i < 4; ++i) {
    p[2*i]   = pack_bf16(v[i].x, v[i].y);
    p[2*i+1] = pack_bf16(v[i].z, v[i].w);
    ss += v[i].x*v[i].x + v[i].y*v[i].y + v[i].z*v[i].z + v[i].w*v[i].w;
  }
  uint4v w0 = {p[0], p[1], p[2], p[3]};
  uint4v w1 = {p[4], p[5], p[6], p[7]};
  uint4v* d4 = (uint4v*)(dst + lane * 16);
  d4[0] = w0; d4[1] = w1;

  #pragma unroll
  for (int off = 32; off > 0; off >>= 1) ss += __shfl_xor(ss, off);
  if (lane == 0) *inv = 1.0f / fmaxf(sqrtf(ss), 1e-8f);
}

// ---------------- Pass 2: 256^2 tile, BK=32, triple-buffer, counted vmcnt ----------------
// LDS per buffer: A[256][32] shorts then B[256][32]; row = 64 B = 4 x 16B chunks.
// Swizzle: position p of row r stores global chunk p ^ ((r>>1)&3)  (involution).
// Staging: wave w stages A rows [w*32, w*32+31] via 2 DMA (16 rows = 1KB each),
//   lane l -> row w*32+16i+(l>>2), pos l&3; source chunk g = (l&3)^((l>>3)&3)
//   (== pos ^ ((row>>1)&3) since (w*16+8i)&3 == 0). LDS dest linear (rule 21).
// Read (32x32x16): frag row = wr*128+m*32+ln, chunk c = 2s+h; pos = c ^ ((ln>>1)&3)
//   ((r>>1)&3 reduces to (ln>>1)&3). Bank spread: (16*(ln&1) + 4*pos) covers all
//   8 4-bank groups x 8 lanes/group per wave64 b128 -> uniform, 2-way free.
// Pipeline: prologue stages tiles 0,1; vmcnt(4); barrier. Iter t: stage t+2 into
//   buf[(t+2)%3] (4 loads/thread), compute buf[t%3], vmcnt(4) (t<NT-2) else
//   vmcnt(0), barrier. Invariant at each boundary: next tile landed, one in flight.
__global__ __launch_bounds__(512, 2) void ca_gemm_bf(
    const unsigned short* __restrict__ Qb,   // [B][SQ][D] bf16
    const unsigned short* __restrict__ Kb,   // [B][SK][D] bf16
    const float* __restrict__ invQ,
    const float* __restrict__ invK,
    const int*   __restrict__ mask,
    float*       __restrict__ out)
{
  __shared__ __align__(16) unsigned short lds[3 * BUFSTRIDE];   // 96 KB

  const int tid  = threadIdx.x;
  const int lane = tid & 63;
  const int w    = tid >> 6;          // 0..7
  const int wr   = w >> 2;            // 0..1  -> rows wr*128..+127
  const int wc   = w & 3;             // 0..3  -> cols wc*64..+63
  const int b    = blockIdx.z;
  const int tm0  = blockIdx.y * BM2;
  const int tn0  = blockIdx.x * BN2;

  // staging source (per-lane, pre-swizzled chunk)
  const int g = (lane & 3) ^ ((lane >> 3) & 3);
  const char* qsrc = (const char*)(Qb + ((size_t)b * SQ + tm0 + w * 32 + (lane >> 2)) * D_) + g * 16;
  const char* ksrc = (const char*)(Kb + ((size_t)b * SK + tn0 + w * 32 + (lane >> 2)) * D_) + g * 16;
  const size_t RSTEP16 = (size_t)16 * D_ * 2;   // 16 rows in bytes

  f32x16 acc[4][2];
  #pragma unroll
  for (int m = 0; m < 4; ++m)
    #pragma unroll
    for (int n = 0; n < 2; ++n)
      #pragma unroll
      for (int r = 0; r < 16; ++r) acc[m][n][r] = 0.0f;

  const int ln = lane & 31;
  const int h  = lane >> 5;
  const int qz = (ln >> 1) & 3;       // swizzle term, row-derived

  auto stage = [&](int bufw) {
    unsigned short* ba = lds + bufw * BUFSTRIDE + w * 1024;   // A rows w*32..
    unsigned short* bb = ba + BUFSH;                          // B rows w*32..
    async_ld16(qsrc,           ba);
    async_ld16(qsrc + RSTEP16, ba + 16 * 32);
    async_ld16(ksrc,           bb);
    async_ld16(ksrc + RSTEP16, bb + 16 * 32);
    qsrc += BK2 * 2;   // advance one K-tile (64 B)
    ksrc += BK2 * 2;
  };

  auto compute = [&](int bufr) {
    const unsigned short* Ab = lds + bufr * BUFSTRIDE + (wr * 128 + ln) * 32;
    const unsigned short* Bb = lds + bufr * BUFSTRIDE + BUFSH + (wc * 64 + ln) * 32;
    #pragma unroll
    for (int s = 0; s < 2; ++s) {
      const int p8 = ((2 * s + h) ^ qz) * 8;
      short8 a0 = *(const short8*)(Ab + p8);
      short8 a1 = *(const short8*)(Ab + p8 + 1024);
      short8 a2 = *(const short8*)(Ab + p8 + 2048);
      short8 a3 = *(const short8*)(Ab + p8 + 3072);
      short8 b0 = *(const short8*)(Bb + p8);
      short8 b1 = *(const short8*)(Bb + p8 + 1024);
      acc[0][0] = __builtin_amdgcn_mfma_f32_32x32x16_bf16(a0, b0, acc[0][0], 0, 0, 0);
      acc[0][1] = __builtin_amdgcn_mfma_f32_32x32x16_bf16(a0, b1, acc[0][1], 0, 0, 0);
      acc[1][0] = __builtin_amdgcn_mfma_f32_32x32x16_bf16(a1, b0, acc[1][0], 0, 0, 0);
      acc[1][1] = __builtin_amdgcn_mfma_f32_32x32x16_bf16(a1, b1, acc[1][1], 0, 0, 0);
      acc[2][0] = __builtin_amdgcn_mfma_f32_32x32x16_bf16(a2, b0, acc[2][0], 0, 0, 0);
      acc[2][1] = __builtin_amdgcn_mfma_f32_32x32x16_bf16(a2, b1, acc[2][1], 0, 0, 0);
      acc[3][0] = __builtin_amdgcn_mfma_f32_32x32x16_bf16(a3, b0, acc[3][0], 0, 0, 0);
      acc[3][1] = __builtin_amdgcn_mfma_f32_32x32x16_bf16(a3, b1, acc[3][1], 0, 0, 0);
    }
  };

  // prologue: stage tiles 0 and 1
  stage(0);
  stage(1);
  asm volatile("s_waitcnt vmcnt(4)" ::: "memory");   // tile 0 landed
  __builtin_amdgcn_s_barrier();

  int bufr = 0, bufw = 2;
  for (int t = 0; t < NT2; ++t) {
    if (t < NT2 - 2) {
      stage(bufw);
      bufw = (bufw == 2) ? 0 : bufw + 1;
    }
    compute(bufr);
    bufr = (bufr == 2) ? 0 : bufr + 1;
    if (t < NT2 - 1) {
      if (t < NT2 - 2) asm volatile("s_waitcnt vmcnt(4)" ::: "memory");  // next tile landed, one in flight
      else             asm volatile("s_waitcnt vmcnt(0)" ::: "memory");  // last tile
      __builtin_amdgcn_s_barrier();
    }
  }

  // Epilogue: 32x32 C/D layout col=lane&31, row=(reg&3)+8*(reg>>2)+4*(lane>>5) [m74/m101].
  #pragma unroll
  for (int n = 0; n < 2; ++n) {
    const int gc = tn0 + wc * 64 + n * 32 + ln;
    const int mk = mask[b * SK + gc];
    const float ibv = invK[b * SK + gc];
    #pragma unroll
    for (int m = 0; m < 4; ++m) {
      #pragma unroll
      for (int reg = 0; reg < 16; ++reg) {
        const int row = wr * 128 + m * 32 + (reg & 3) + 8 * (reg >> 2) + 4 * h;
        const float iav = invQ[b * SQ + tm0 + row];
        float v = mk ? acc[m][n][reg] * iav * ibv : -1000000000.0f;
        out[((size_t)b * SQ + tm0 + row) * SK + gc] = v;
      }
    }
  }
}

// ---------------- Fallback: single-kernel bf16, LDK=40 ----------------
constexpr int LDK = 40;

__global__ __launch_bounds__(256, 2) void ca_gemm(
    const float* __restrict__ Q, const float* __restrict__ Km,
    const int* __restrict__ mask, float* __restrict__ out)
{
  __shared__ __align__(16) short As[BM * LDK];
  __shared__ __align__(16) short Bs[BN * LDK];
  __shared__ float ssA_part[256];
  __shared__ float ssB_part[256];
  __shared__ float invA[BM];
  __shared__ float invB[BN];

  const int tid  = threadIdx.x;
  const int lane = tid & 63;
  const int w    = tid >> 6;
  const int b    = blockIdx.z;
  const int tm0  = blockIdx.y * BM;
  const int tn0  = blockIdx.x * BN;

  const int ra = tid >> 1;
  const int ka = (tid & 1) * 16;

  const float* qp = Q  + ((size_t)b * SQ + tm0 + ra) * D_ + ka;
  const float* kp = Km + ((size_t)b * SK + tn0 + ra) * D_ + ka;

  f32x4 zero4 = {0.0f, 0.0f, 0.0f, 0.0f};
  f32x4 acc[4][4];
  #pragma unroll
  for (int i = 0; i < 4; ++i)
    #pragma unroll
    for (int j = 0; j < 4; ++j) acc[i][j] = zero4;

  float ssA = 0.0f, ssB = 0.0f;

  const int wm = (w >> 1) * 64;
  const int wn = (w & 1) * 64;
  const int lr = lane & 15;
  const int lq = lane >> 4;

  short* aw = &As[ra * LDK + ka];
  short* bw = &Bs[ra * LDK + ka];

  for (int k0 = 0; k0 < D_; k0 += 32) {
    f32x4 av[4], bv[4];
    #pragma unroll
    for (int i = 0; i < 4; ++i) av[i] = *(const f32x4*)(qp + 4 * i);
    #pragma unroll
    for (int i = 0; i < 4; ++i) bv[i] = *(const f32x4*)(kp + 4 * i);
    qp += 32; kp += 32;

    unsigned pa[8], pb[8];
    #pragma unroll
    for (int i = 0; i < 4; ++i) {
      pa[2*i]   = pack_bf16(av[i].x, av[i].y);
      pa[2*i+1] = pack_bf16(av[i].z, av[i].w);
      pb[2*i]   = pack_bf16(bv[i].x, bv[i].y);
      pb[2*i+1] = pack_bf16(bv[i].z, bv[i].w);
      ssA += av[i].x*av[i].x + av[i].y*av[i].y + av[i].z*av[i].z + av[i].w*av[i].w;
      ssB += bv[i].x*bv[i].x + bv[i].y*bv[i].y + bv[i].z*bv[i].z + bv[i].w*bv[i].w;
    }

    __syncthreads();
    {
      uint4v wa0 = {pa[0], pa[1], pa[2], pa[3]};
      uint4v wa1 = {pa[4], pa[5], pa[6], pa[7]};
      uint4v wb0 = {pb[0], pb[1], pb[2], pb[3]};
      uint4v wb1 = {pb[4], pb[5], pb[6], pb[7]};
      *(uint4v*)(aw)     = wa0;
      *(uint4v*)(aw + 8) = wa1;
      *(uint4v*)(bw)     = wb0;
      *(uint4v*)(bw + 8) = wb1;
    }
    __syncthreads();

    short8 af[4], bf[4];
    #pragma unroll
    for (int t = 0; t < 4; ++t)
      af[t] = *(const short8*)&As[(wm + t * 16 + lr) * LDK + lq * 8];
    #pragma unroll
    for (int t = 0; t < 4; ++t)
      bf[t] = *(const short8*)&Bs[(wn + t * 16 + lr) * LDK + lq * 8];

    #pragma unroll
    for (int i = 0; i < 4; ++i)
      #pragma unroll
      for (int j = 0; j < 4; ++j)
        acc[i][j] = __builtin_amdgcn_mfma_f32_16x16x32_bf16(af[i], bf[j], acc[i][j], 0, 0, 0);
  }

  ssA_part[tid] = ssA;
  ssB_part[tid] = ssB;
  __syncthreads();
  if (tid < BM) {
    float s = ssA_part[2 * tid] + ssA_part[2 * tid + 1];
    invA[tid] = 1.0f / fmaxf(sqrtf(s), 1e-8f);
  } else {
    int r = tid - BM;
    float s = ssB_part[2 * r] + ssB_part[2 * r + 1];
    invB[r] = 1.0f / fmaxf(sqrtf(s), 1e-8f);
  }
  __syncthreads();

  #pragma unroll
  for (int tn = 0; tn < 4; ++tn) {
    const int lc = wn + tn * 16 + lr;
    const int gc = tn0 + lc;
    const int mk = mask[b * SK + gc];
    const float ibv = invB[lc];
    #pragma unroll
    for (int tm = 0; tm < 4; ++tm) {
      const int lrow = wm + tm * 16 + lq * 4;
      #pragma unroll
      for (int r = 0; r < 4; ++r) {
        float v = mk ? acc[tm][tn][r] * invA[lrow + r] * ibv : -1000000000.0f;
        out[((size_t)b * SQ + tm0 + lrow + r) * SK + gc] = v;
      }
    }
  }
}

extern "C" void kernel_launch(void* const* d_in, const int* in_sizes, int n_in,
                              void* d_out, int out_size, void* d_ws, size_t ws_size,
                              hipStream_t stream) {
  const float* Q    = (const float*)d_in[0];
  const float* Km   = (const float*)d_in[1];
  const int*   mask = (const int*)d_in[2];
  float*       out  = (float*)d_out;

  const size_t nQ   = (size_t)B_ * SQ * D_;        // elements
  const size_t nK   = (size_t)B_ * SK * D_;
  const size_t need = (nQ + nK) * 2 + (size_t)B_ * (SQ + SK) * 4;
  if (ws_size >= need) {
    unsigned short* Qb = (unsigned short*)d_ws;
    unsigned short* Kb = Qb + nQ;
    float*          iQ = (float*)(Kb + nK);
    float*          iK = iQ + (size_t)B_ * SQ;
    convert_norm<<<ROWS_T / 4, 256, 0, stream>>>(Q, Km, Qb, Kb, iQ, iK);
    dim3 grid(SK / BN2, SQ / BM2, B_);
    ca_gemm_bf<<<grid, dim3(512), 0, stream>>>(Qb, Kb, iQ, iK, mask, out);
  } else {
    dim3 grid(SK / BN, SQ / BM, B_);
    ca_gemm<<<grid, dim3(256), 0, stream>>>(Q, Km, mask, out);
  }
}